// Round 13
// baseline (113.429 us; speedup 1.0000x reference)
//
#include <hip/hip_runtime.h>
#include <hip/hip_bf16.h>

#define B_ 8
#define N_ 512
#define F_ 128
#define H_ 4
#define U_ 32
#define LEAKY_ALPHA 0.2f

typedef __attribute__((ext_vector_type(8))) short short8;
typedef __attribute__((ext_vector_type(4))) short short4v;
typedef __attribute__((ext_vector_type(4))) float f32x4;

static __device__ __forceinline__ short f2bf_s(float x) {
    __hip_bfloat16 hv = __float2bfloat16(x);
    return *reinterpret_cast<short*>(&hv);
}
static __device__ __forceinline__ float bf2f_s(short v) {
    return __uint_as_float(((unsigned)(unsigned short)v) << 16);
}
#define PINF4(v) asm volatile("" : "+v"(v.x), "+v"(v.y), "+v"(v.z), "+v"(v.w))

// ---------------------------------------------------------------------------
// Kernel 1: projections (R12 version — measured equal-best).
//   hsrc   = x@Wsrc (f32)           [bh][n][u]
//   hsrcT  = bf16(x@Wsrc)^T         [bh*32+u][n]  (MFMA B-frag layout)
//   hdstNT = -(x@Wdst) (f32)^T      [bh*32+u][j]  (coalesced per-lane d-rows)
//   Drow[j] = sum_u a_u d_ju ; ascaled = 0.8*a
// score(i,j) ~ D_j + sum_u (0.8 a_u) max(s_iu, -d_ju)  (0.2*A_i dropped;
// softmax shift-invariant).
// ---------------------------------------------------------------------------
__global__ __launch_bounds__(512) void proj_kernel(
    const float* __restrict__ x, const float* __restrict__ Wsrc,
    const float* __restrict__ Wdst, const float* __restrict__ a,
    float* __restrict__ hsrc, float* __restrict__ hdstNT,
    float* __restrict__ Drow, float* __restrict__ ascaled,
    short* __restrict__ hsrcT)
{
    __shared__ float4 xlds[16 * 32];
    const int t  = threadIdx.x;
    const int r0 = blockIdx.x * 16;

    xlds[t] = ((const float4*)x)[(size_t)r0 * 32 + t];
    __syncthreads();

    const int u  = t & 31;
    const int h  = (t >> 5) & 3;
    const int rq = t >> 7;
    const float* Ws = Wsrc + h * (F_ * U_) + u;
    const float* Wd = Wdst + h * (F_ * U_) + u;

    float as[4], ad[4];
#pragma unroll
    for (int r = 0; r < 4; ++r) { as[r] = 0.f; ad[r] = 0.f; }

#pragma unroll 2
    for (int fc = 0; fc < 32; ++fc) {
        const float s0 = Ws[(4 * fc + 0) * U_];
        const float s1 = Ws[(4 * fc + 1) * U_];
        const float s2 = Ws[(4 * fc + 2) * U_];
        const float s3 = Ws[(4 * fc + 3) * U_];
        const float d0 = Wd[(4 * fc + 0) * U_];
        const float d1 = Wd[(4 * fc + 1) * U_];
        const float d2 = Wd[(4 * fc + 2) * U_];
        const float d3 = Wd[(4 * fc + 3) * U_];
#pragma unroll
        for (int r = 0; r < 4; ++r) {
            const float4 xv = xlds[(rq * 4 + r) * 32 + fc];
            float vs = as[r], vd = ad[r];
            vs = fmaf(xv.x, s0, vs);  vd = fmaf(xv.x, d0, vd);
            vs = fmaf(xv.y, s1, vs);  vd = fmaf(xv.y, d1, vd);
            vs = fmaf(xv.z, s2, vs);  vd = fmaf(xv.z, d2, vd);
            vs = fmaf(xv.w, s3, vs);  vd = fmaf(xv.w, d3, vd);
            as[r] = vs; ad[r] = vd;
        }
    }

    const float av = a[h * U_ + u];
    if (t < 128 && blockIdx.x == 0)
        ascaled[h * U_ + u] = (1.f - LEAKY_ALPHA) * av;

    const int b  = r0 >> 9;
    const int n0 = (r0 & (N_ - 1)) + rq * 4;
    const int bh = b * H_ + h;

    short4v pk;
#pragma unroll
    for (int r = 0; r < 4; ++r) {
        hsrc[((size_t)(bh * N_ + n0 + r) << 5) + u] = as[r];
        pk[r] = f2bf_s(as[r]);
    }
    *(short4v*)&hsrcT[((size_t)(bh * U_) + u) * N_ + n0] = pk;

    float4 nv;
    nv.x = -ad[0]; nv.y = -ad[1]; nv.z = -ad[2]; nv.w = -ad[3];
    *(float4*)&hdstNT[((size_t)(bh * U_) + u) * N_ + n0] = nv;

#pragma unroll
    for (int r = 0; r < 4; ++r) {
        float v = ad[r] * av;
        v += __shfl_xor(v, 1);
        v += __shfl_xor(v, 2);
        v += __shfl_xor(v, 4);
        v += __shfl_xor(v, 8);
        v += __shfl_xor(v, 16);
        if (u == 0) Drow[bh * N_ + n0 + r] = v;
    }
}

// ---------------------------------------------------------------------------
// Kernel 2a: attnA — scores -> exp -> p (bf16) to GLOBAL. Zero LDS, zero
// barriers, waves fully independent. Lane = j owns one pinned d-row; 0.8*a
// hoisted+pinned in VGPRs; s-rows block-uniform (scalar path); Dj folded
// into the accumulator init. Diagnostic split: this dispatch's counters
// finally isolate the score stream.
// Grid = 1024 (32 bh x 32 tile16), 512 thr.
// ---------------------------------------------------------------------------
__global__ __launch_bounds__(512, 4) void attnA_kernel(
    const float* __restrict__ hsrc, const float* __restrict__ hdstNT,
    const float* __restrict__ Drow, const float* __restrict__ ascaled,
    short* __restrict__ pG)
{
    const int t    = threadIdx.x;
    const int bid  = blockIdx.x;
    const int tile = bid & 31;
    const int bh   = bid >> 5;
    const int h    = bh & 3;
    const size_t bhN = (size_t)bh * N_;
    const int ig0  = tile * 16;
    const int j    = t;

    // per-lane d-row (coalesced, pinned)
    const float* dT = hdstNT + ((size_t)bh * U_) * N_ + j;
#define DL(k) float d##k = dT[(k) * N_];
    DL(0) DL(1) DL(2) DL(3) DL(4) DL(5) DL(6) DL(7)
    DL(8) DL(9) DL(10) DL(11) DL(12) DL(13) DL(14) DL(15)
    DL(16) DL(17) DL(18) DL(19) DL(20) DL(21) DL(22) DL(23)
    DL(24) DL(25) DL(26) DL(27) DL(28) DL(29) DL(30) DL(31)
#undef DL
#define PIN4(a0,a1,a2,a3) asm volatile("" : "+v"(a0), "+v"(a1), "+v"(a2), "+v"(a3));
    PIN4(d0,d1,d2,d3)     PIN4(d4,d5,d6,d7)
    PIN4(d8,d9,d10,d11)   PIN4(d12,d13,d14,d15)
    PIN4(d16,d17,d18,d19) PIN4(d20,d21,d22,d23)
    PIN4(d24,d25,d26,d27) PIN4(d28,d29,d30,d31)
#undef PIN4

    // 0.8*a hoisted + pinned (kills any per-i reloads)
    float4 av4[8];
    {
        const float4* ag = (const float4*)(ascaled + h * U_);
#pragma unroll
        for (int q = 0; q < 8; ++q) av4[q] = ag[q];
#pragma unroll
        for (int q = 0; q < 8; ++q) PINF4(av4[q]);
    }

    const float Dj = Drow[bhN + j];
    const float* sB = hsrc + ((bhN + ig0) << 5);   // block-uniform
    short* pOut = pG + (size_t)bid * (16 * N_) + j;

#define T_(av, sk, dk, accv) accv = fmaf(av, fmaxf(sR[sk], dk), accv);
#pragma unroll 2
    for (int i = 0; i < 16; ++i) {
        const float* sR = sB + (i << 5);
        float acA = Dj, acB = 0.f;
        T_(av4[0].x, 0,  d0,  acA) T_(av4[0].y, 1,  d1,  acB)
        T_(av4[0].z, 2,  d2,  acA) T_(av4[0].w, 3,  d3,  acB)
        T_(av4[1].x, 4,  d4,  acA) T_(av4[1].y, 5,  d5,  acB)
        T_(av4[1].z, 6,  d6,  acA) T_(av4[1].w, 7,  d7,  acB)
        T_(av4[2].x, 8,  d8,  acA) T_(av4[2].y, 9,  d9,  acB)
        T_(av4[2].z, 10, d10, acA) T_(av4[2].w, 11, d11, acB)
        T_(av4[3].x, 12, d12, acA) T_(av4[3].y, 13, d13, acB)
        T_(av4[3].z, 14, d14, acA) T_(av4[3].w, 15, d15, acB)
        T_(av4[4].x, 16, d16, acA) T_(av4[4].y, 17, d17, acB)
        T_(av4[4].z, 18, d18, acA) T_(av4[4].w, 19, d19, acB)
        T_(av4[5].x, 20, d20, acA) T_(av4[5].y, 21, d21, acB)
        T_(av4[5].z, 22, d22, acA) T_(av4[5].w, 23, d23, acB)
        T_(av4[6].x, 24, d24, acA) T_(av4[6].y, 25, d25, acB)
        T_(av4[6].z, 26, d26, acA) T_(av4[6].w, 27, d27, acB)
        T_(av4[7].x, 28, d28, acA) T_(av4[7].y, 29, d29, acB)
        T_(av4[7].z, 30, d30, acA) T_(av4[7].w, 31, d31, acB)
        pOut[i * N_] = f2bf_s(__expf(acA + acB));
    }
#undef T_
}

// ---------------------------------------------------------------------------
// Kernel 2b: attnC — l-reduce (from global p, L2-warm) + MFMA PV + out.
// Grid = 1024 blocks x 256 thr (4 waves). Wave w = (nt = w&1, ks = w>>1),
// K = 256 per wave (8 MFMA); cross-wave K-reduce via 4 KB LDS scr.
// ---------------------------------------------------------------------------
__global__ __launch_bounds__(256, 4) void attnC_kernel(
    const short* __restrict__ pG, const short* __restrict__ hsrcT,
    float* __restrict__ out)
{
    __shared__ f32x4 scr[4][64];
    __shared__ float lfin[16];

    const int t    = threadIdx.x;
    const int L    = t & 63;
    const int w    = __builtin_amdgcn_readfirstlane(t >> 6);
    const int bid  = blockIdx.x;
    const int tile = bid & 31;
    const int bh   = bid >> 5;
    const int h    = bh & 3;
    const int b    = bh >> 2;
    const int ig0  = tile * 16;
    const short* pBase = pG + (size_t)bid * (16 * N_);

    // ---- l reduce: thread (ri = t>>4, rg = t&15) sums 32 j of row ri ----
    {
        const int ri = t >> 4;
        const int rg = t & 15;
        const short8* pr = (const short8*)(pBase + ri * N_ + rg * 32);
        float sum = 0.f;
#pragma unroll
        for (int q = 0; q < 4; ++q) {
            const short8 pv = pr[q];
#pragma unroll
            for (int k = 0; k < 8; ++k) sum += bf2f_s(pv[k]);
        }
        sum += __shfl_xor(sum, 1);
        sum += __shfl_xor(sum, 2);
        sum += __shfl_xor(sum, 4);
        sum += __shfl_xor(sum, 8);
        if (rg == 0) lfin[ri] = __builtin_amdgcn_rcpf(sum);
    }
    __syncthreads();

    // ---- MFMA: out = p[16x512] @ srcT ----
    const int m  = L & 15;
    const int kq = L >> 4;
    const int nt = w & 1;
    const int ks = w >> 1;
    const short* Ap = pBase + m * N_ + ks * 256 + kq * 8;
    const short* Bp = hsrcT + ((size_t)bh * U_ + nt * 16 + m) * N_ + ks * 256 + kq * 8;

    f32x4 acc = {0.f, 0.f, 0.f, 0.f};
#pragma unroll
    for (int st = 0; st < 8; ++st) {
        const short8 af = *(const short8*)(Ap + st * 32);
        const short8 bf = *(const short8*)(Bp + st * 32);
        acc = __builtin_amdgcn_mfma_f32_16x16x32_bf16(af, bf, acc, 0, 0, 0);
    }
    scr[w][L] = acc;
    __syncthreads();

    if (w < 2) {                               // wave w reduces ntile=w
        f32x4 s0 = scr[w][L];
        const f32x4 s1 = scr[w + 2][L];
        s0 += s1;
#pragma unroll
        for (int r = 0; r < 4; ++r) {
            const int il = kq * 4 + r;         // C/D: row=(lane>>4)*4+reg
            out[((size_t)(b * N_ + ig0 + il)) * (H_ * U_) + h * U_ + w * 16 + m]
                = s0[r] * lfin[il];
        }
    }
}

// ---------------------------------------------------------------------------
extern "C" void kernel_launch(void* const* d_in, const int* in_sizes, int n_in,
                              void* d_out, int out_size, void* d_ws, size_t ws_size,
                              hipStream_t stream) {
    const float* x    = (const float*)d_in[0];
    const float* Wsrc = (const float*)d_in[1];
    const float* Wdst = (const float*)d_in[2];
    const float* a    = (const float*)d_in[3];

    float* ws      = (float*)d_ws;
    float* hsrc    = ws;                                   // 524288 f
    float* hdstNT  = hsrc + (size_t)B_ * H_ * N_ * U_;     // 524288 f
    float* Drow    = hdstNT + (size_t)B_ * H_ * U_ * N_;   // 16384 f
    float* ascaled = Drow + (size_t)B_ * H_ * N_;          // 128 f
    short* hsrcT   = (short*)(ascaled + H_ * U_);          // 524288 sh
    short* pG      = hsrcT + (size_t)B_ * H_ * U_ * N_;    // 8388608 sh

    proj_kernel<<<(B_ * N_) / 16, 512, 0, stream>>>(x, Wsrc, Wdst, a,
                                                    hsrc, hdstNT, Drow, ascaled,
                                                    hsrcT);
    attnA_kernel<<<B_ * H_ * (N_ / 16), 512, 0, stream>>>(hsrc, hdstNT, Drow,
                                                          ascaled, pG);
    attnC_kernel<<<B_ * H_ * (N_ / 16), 256, 0, stream>>>(pG, hsrcT,
                                                          (float*)d_out);
}